// Round 1
// baseline (41.574 us; speedup 1.0000x reference)
//
#include <hip/hip_runtime.h>
#include <hip/hip_fp16.h>

// Problem constants
#define B_TOT 65536
#define I_DIM 128     // K
#define N_DIM 256
#define BM    64      // batch rows per block
#define NTHR  256

typedef __attribute__((ext_vector_type(8))) _Float16 half8;
typedef __attribute__((ext_vector_type(4))) _Float16 half4;
typedef __attribute__((ext_vector_type(4))) float    f32x4;

__device__ inline float fast_exp2(float x) {
#if __has_builtin(__builtin_amdgcn_exp2f)
  return __builtin_amdgcn_exp2f(x);
#else
  return exp2f(x);
#endif
}
__device__ inline float fast_rcp(float x) {
#if __has_builtin(__builtin_amdgcn_rcpf)
  return __builtin_amdgcn_rcpf(x);
#else
  return 1.0f / x;
#endif
}

// ws layout:
//   [0, 65536)        : W_in as fp16, row-major [256][128], XOR-swizzled 16B chunks
//   [65536, 65536+5KB): per-neuron params: wm[256], bias[256], nsl[256], A[256], nt[256]
__global__ void prep_kernel(const float* __restrict__ W_in, const float* __restrict__ w_rec,
                            const void* __restrict__ mask, const float* __restrict__ bias,
                            const float* __restrict__ tau, const float* __restrict__ Aamp,
                            const float* __restrict__ sigma, char* __restrict__ ws) {
  __shared__ int flag;
  const int t = threadIdx.x;

  if (blockIdx.x == 0) {
    // ---- mask dtype detection: reads stay within 256 bytes under either layout ----
    if (t == 0) flag = 0;
    __syncthreads();
    if (t < 64) {
      int w = ((const int*)mask)[t];
      if (w != 0 && w != 1) atomicOr(&flag, 1);
    }
    __syncthreads();
    const bool as_bytes = (flag != 0);
    const int nn = t;  // one neuron per thread
    float mv = as_bytes ? (float)(((const unsigned char*)mask)[nn])
                        : (float)(((const int*)mask)[nn]);
    float* P = (float*)(ws + 65536);
    P[nn]         = w_rec[nn] * mv;                          // wm (sparsity-masked)
    P[256 + nn]   = bias[nn];                                 // bias
    P[512 + nn]   = -sigma[nn] * 1.44269504088896340736f;     // -sigma*log2(e)
    P[768 + nn]   = Aamp[nn];                                 // A
    P[1024 + nn]  = -1.0f / tau[nn];                          // -1/tau
  }

  // ---- W_in fp32 -> fp16, swizzled, coalesced reads ----
  int f4 = blockIdx.x * NTHR + t;            // 0..8191 float4s (256*128/4)
  float4 v = ((const float4*)W_in)[f4];
  int row  = f4 >> 5;                         // neuron row (32 float4 per row)
  int col4 = f4 & 31;
  half4 hv;
  hv[0] = (_Float16)v.x; hv[1] = (_Float16)v.y;
  hv[2] = (_Float16)v.z; hv[3] = (_Float16)v.w;
  int byteoff = row * 256 + ((((col4 >> 1) ^ (row & 7)) << 4) | ((col4 & 1) << 3));
  *(half4*)(ws + byteoff) = hv;
}

// RK4 for one element. dx/dt = -x/tau + sigmoid(sigma*(ic + x*wm + b))*(A - x)
__device__ inline float rk4_one(float ic, float bi, float wm, float nsl,
                                float Aa, float nt, float h0) {
  const float icb = ic + bi;
  auto ode = [&](float s) {
    float tot = fmaf(s, wm, icb);
    float e   = fast_exp2(nsl * tot);         // exp(-sigma*tot)
    float f   = fast_rcp(1.0f + e);           // sigmoid
    return fmaf(f, Aa - s, s * nt);
  };
  float k1 = ode(h0);
  float k2 = ode(fmaf(0.5f, k1, h0));
  float k3 = ode(fmaf(0.5f, k2, h0));
  float k4 = ode(h0 + k3);
  return fmaf(fmaf(2.0f, k2 + k3, k1 + k4), 0.16666666666666666f, h0);
}

__launch_bounds__(NTHR, 2)
__global__ void liquid_kernel(const float* __restrict__ x, const float* __restrict__ h,
                              const char* __restrict__ ws, float* __restrict__ out) {
  // LDS: sA [64][128] fp16 (16KB, swizzled) | sB [256][128] fp16 (64KB, swizzled),
  // sB later reused as sIC [64][256] f32 (64KB, swizzled)
  __shared__ char smem[81920];
  char*  sA  = smem;
  char*  sB  = smem + 16384;
  float* sIC = (float*)(smem + 16384);

  const int t    = threadIdx.x;
  const int b0   = blockIdx.x * BM;
  const int wave = t >> 6;
  const int lane = t & 63;
  const int lr   = lane & 15;   // row/col within fragment
  const int lk   = lane >> 4;   // k segment / acc row group

  // ---- per-thread neuron params (each thread always handles neurons 4*(t&63)..+3) ----
  const float* P = (const float*)(ws + 65536);
  const int n4 = t & 63;
  const float4 wm4 = *(const float4*)(P + n4 * 4);
  const float4 bi4 = *(const float4*)(P + 256 + n4 * 4);
  const float4 sl4 = *(const float4*)(P + 512 + n4 * 4);
  const float4 Aa4 = *(const float4*)(P + 768 + n4 * 4);
  const float4 nt4 = *(const float4*)(P + 1024 + n4 * 4);

  // ---- stage x tile -> sA (fp16, swizzled) ----
  {
    const float4* xg = (const float4*)(x + (size_t)b0 * I_DIM);
#pragma unroll
    for (int i = 0; i < 8; ++i) {
      int idx  = t + i * NTHR;        // float4 index in [64][32]
      float4 v = xg[idx];
      int row  = idx >> 5;
      int col4 = idx & 31;
      half4 hv;
      hv[0] = (_Float16)v.x; hv[1] = (_Float16)v.y;
      hv[2] = (_Float16)v.z; hv[3] = (_Float16)v.w;
      int byteoff = row * 256 + ((((col4 >> 1) ^ (row & 7)) << 4) | ((col4 & 1) << 3));
      *(half4*)(sA + byteoff) = hv;
    }
    // ---- stage W -> sB: linear copy (ws already fp16 + swizzled) ----
    const float4* wg  = (const float4*)ws;
    float4*       sB4 = (float4*)sB;
#pragma unroll
    for (int i = 0; i < 16; ++i) {
      int idx = t + i * NTHR;
      sB4[idx] = wg[idx];
    }
  }
  __syncthreads();

  // ---- GEMM: each wave owns 64 rows x 64 cols (cols = wave*64..+63) ----
  f32x4 acc[4][4] = {};
#pragma unroll
  for (int k = 0; k < 4; ++k) {
    half8 a[4], b[4];
    const int chunk = k * 4 + lk;
#pragma unroll
    for (int m = 0; m < 4; ++m) {
      int row = m * 16 + lr;
      a[m] = *(const half8*)(sA + row * 256 + ((chunk ^ (row & 7)) << 4));
    }
#pragma unroll
    for (int n = 0; n < 4; ++n) {
      int row = wave * 64 + n * 16 + lr;     // W row = neuron
      b[n] = *(const half8*)(sB + row * 256 + ((chunk ^ (row & 7)) << 4));
    }
#pragma unroll
    for (int m = 0; m < 4; ++m)
#pragma unroll
      for (int n = 0; n < 4; ++n)
        acc[m][n] = __builtin_amdgcn_mfma_f32_16x16x32_f16(a[m], b[n], acc[m][n], 0, 0, 0);
  }
  __syncthreads();   // all waves done reading sB before overwrite

  // ---- write ic -> sIC (f32, swizzled: dword_col ^= ((row>>2)&3)<<4) ----
#pragma unroll
  for (int m = 0; m < 4; ++m) {
    const int rbase = m * 16 + lk * 4;
#pragma unroll
    for (int n = 0; n < 4; ++n) {
      const int colx = (wave * 64 + n * 16 + lr) ^ (lk << 4);
#pragma unroll
      for (int r = 0; r < 4; ++r)
        sIC[(rbase + r) * 256 + colx] = acc[m][n][r];
    }
  }
  __syncthreads();

  // ---- fused RK4 epilogue: coalesced float4 over contiguous [64][256] tile ----
  const float4* hg = (const float4*)(h + (size_t)b0 * N_DIM);
  float4*       og = (float4*)(out + (size_t)b0 * N_DIM);
#pragma unroll
  for (int i = 0; i < 16; ++i) {
    int f4  = t + i * NTHR;
    int row = f4 >> 6;
    int dw  = row * 256 + ((n4 * 4) ^ (((row >> 2) & 3) << 4));
    float4 ic4 = *(const float4*)(sIC + dw);
    float4 h4  = hg[f4];
    float4 o4;
    o4.x = rk4_one(ic4.x, bi4.x, wm4.x, sl4.x, Aa4.x, nt4.x, h4.x);
    o4.y = rk4_one(ic4.y, bi4.y, wm4.y, sl4.y, Aa4.y, nt4.y, h4.y);
    o4.z = rk4_one(ic4.z, bi4.z, wm4.z, sl4.z, Aa4.z, nt4.z, h4.z);
    o4.w = rk4_one(ic4.w, bi4.w, wm4.w, sl4.w, Aa4.w, nt4.w, h4.w);
    og[f4] = o4;
  }
}

extern "C" void kernel_launch(void* const* d_in, const int* in_sizes, int n_in,
                              void* d_out, int out_size, void* d_ws, size_t ws_size,
                              hipStream_t stream) {
  const float* x     = (const float*)d_in[0];
  const float* h     = (const float*)d_in[1];
  const float* W_in  = (const float*)d_in[2];
  const float* w_rec = (const float*)d_in[3];
  const void*  mask  = d_in[4];
  const float* bias  = (const float*)d_in[5];
  const float* tau   = (const float*)d_in[6];
  const float* A     = (const float*)d_in[7];
  const float* sigma = (const float*)d_in[8];
  float* out = (float*)d_out;
  char*  ws  = (char*)d_ws;

  prep_kernel<<<32, NTHR, 0, stream>>>(W_in, w_rec, mask, bias, tau, A, sigma, ws);
  liquid_kernel<<<B_TOT / BM, NTHR, 0, stream>>>(x, h, ws, out);
}